// Round 11
// baseline (208.237 us; speedup 1.0000x reference)
//
#include <hip/hip_runtime.h>
#include <stdint.h>
#include <math.h>

// Problem constants (fixed by setup_inputs)
#define B_ROWS 16384
#define D_DIM  1024
#define OUT_N  4096

typedef __bf16 bf16x8 __attribute__((ext_vector_type(8)));
typedef float  f32x4  __attribute__((ext_vector_type(4)));

__device__ __forceinline__ unsigned short f2bf(float f) {
  union { float f; uint32_t u; } v; v.f = f;
  uint32_t u = v.u;
  u += 0x7FFFu + ((u >> 16) & 1u);   // round-to-nearest-even
  return (unsigned short)(u >> 16);
}

// ---------------- prep kernel: one row per wave, no LDS/barriers ----------------
__global__ void prep_kernel(const float* __restrict__ x,
                            const float* __restrict__ z,
                            const float* __restrict__ r,
                            const float* __restrict__ bias,
                            unsigned short* __restrict__ xbf,
                            unsigned short* __restrict__ zbf,
                            float* __restrict__ beta,
                            float4* __restrict__ zp) {
  const int wave = threadIdx.x >> 6;
  const int lane = threadIdx.x & 63;
  const int b = blockIdx.x * 4 + wave;        // global row id
  const bool isx = (b < B_ROWS);
  const int row = isx ? b : (b - B_ROWS);
  const float* src = (isx ? x : z) + (size_t)row * D_DIM;
  unsigned short* dst = (isx ? xbf : zbf) + (size_t)row * D_DIM;

  float ssq = 0.0f;
#pragma unroll
  for (int i = 0; i < 4; ++i) {
    const float4 v = reinterpret_cast<const float4*>(src)[i * 64 + lane];
    ssq += v.x * v.x + v.y * v.y + v.z * v.z + v.w * v.w;
    ushort4 h;
    h.x = f2bf(v.x); h.y = f2bf(v.y); h.z = f2bf(v.z); h.w = f2bf(v.w);
    reinterpret_cast<ushort4*>(dst)[i * 64 + lane] = h;
  }
#pragma unroll
  for (int off = 32; off > 0; off >>= 1) ssq += __shfl_down(ssq, off);
  if (lane == 0) {
    if (isx) {
      beta[row] = sqrtf(1.0f + ssq);   // sqrt(1 - K*x^2), K = -1
    } else {
      float zn = fmaxf(sqrtf(ssq), 1e-15f);
      float sr = fminf(fmaxf(r[row], -15.0f), 15.0f);
      float ch = coshf(sr), sh = sinhf(sr);
      const float LOG2E = 1.4426950408889634f;
      zp[row] = make_float4(ch / zn, sh, zn, bias[row] * LOG2E);
    }
  }
}

// ---------------- fused GEMM: 128x256 tile, BK=32, 3-buf rotation, 2 blocks/CU ----------------

__device__ __forceinline__ void gload_lds16(const void* g, void* l) {
  __builtin_amdgcn_global_load_lds((__attribute__((address_space(1))) void*)g,
                                   (__attribute__((address_space(3))) void*)l,
                                   16, 0, 0);
}

#define FENCE() asm volatile("" ::: "memory")
#define BARRIER() do { FENCE(); __builtin_amdgcn_s_barrier(); FENCE(); } while (0)

// LDS (ushort offsets), per buffer (stride 12288 = 24 KB):
//   A: [64 rowpairs][8 chunks16B]  = 4096 ushorts  (128 rows x 32 cols bf16)
//   B: [128 rowpairs][8 chunks16B] = 8192 ushorts  (256 rows x 32 cols), at +4096
// Swizzle: logical chunk l of rowpair rp lives at phys chunk l ^ (rp&7).
//   logical l = (row&1)*4 + k_octet  (octet = 8 bf16 = 16B)
// Full-wave b128 frag reads touch each (rp,phys) slot once -> 2-way max (free).
// Staging writes are LINEAR in slots (gload_lds constraint); the inverse
// swizzle is applied to the per-lane GLOBAL source address (rule #21).

// per-thread staging context: 3 chunks/thread/K-tile (A slot s, B slots s, s+512)
struct Stage {
  const unsigned short *asrc, *bsrc0, *bsrc1;  // row+octet folded in
  int dofs;                                    // wave*512 (ushort)
};

__device__ __forceinline__ void do_stage(const Stage& st, unsigned short* lds,
                                         int bufS, int k0) {
  gload_lds16(st.asrc  + k0, lds + bufS + st.dofs);
  gload_lds16(st.bsrc0 + k0, lds + bufS + 4096 + st.dofs);
  gload_lds16(st.bsrc1 + k0, lds + bufS + 8192 + st.dofs);
}

template <int BUFR, int BUFS, bool STG, int VMN>
__device__ __forceinline__ void body(f32x4 acc[4][4], const unsigned short* lds,
                                     const int aofs[4], const int bofs[4],
                                     const Stage& st, unsigned short* ldsw, int k0) {
  if (VMN == 0) asm volatile("s_waitcnt vmcnt(0)" ::: "memory");
  else          asm volatile("s_waitcnt vmcnt(3)" ::: "memory");
  BARRIER();
  bf16x8 af[4], bf_[4];
#pragma unroll
  for (int mi = 0; mi < 4; ++mi)
    af[mi] = *reinterpret_cast<const bf16x8*>(&lds[BUFR + aofs[mi]]);
#pragma unroll
  for (int ni = 0; ni < 4; ++ni)
    bf_[ni] = *reinterpret_cast<const bf16x8*>(&lds[BUFR + bofs[ni]]);
  if (STG) do_stage(st, ldsw, BUFS, k0);
  __builtin_amdgcn_s_setprio(1);
#pragma unroll
  for (int mi = 0; mi < 4; ++mi)
#pragma unroll
    for (int ni = 0; ni < 4; ++ni)
      acc[mi][ni] = __builtin_amdgcn_mfma_f32_16x16x32_bf16(
          af[mi], bf_[ni], acc[mi][ni], 0, 0, 0);
  __builtin_amdgcn_s_setprio(0);
}

// 2 blocks/CU: LDS 72 KB/block, __launch_bounds__(512,4) -> 128-reg budget.
// RACE-FREE BY ROTATION: phase t reads buf(t%3), stages tile t+2 into
// buf((t+2)%3) = the buffer whose reads drained during phase t-1 (before the
// barrier we just crossed). No phase reads and re-stages the same region.
__global__ __launch_bounds__(512, 4) void gemm_fused(
    const unsigned short* __restrict__ xbf,
    const unsigned short* __restrict__ zbf,
    const float* __restrict__ beta,
    const float4* __restrict__ zp,
    float* __restrict__ out) {
  __shared__ unsigned short lds[36864];   // 72 KB = 3 bufs x 24 KB

  const int t = threadIdx.x;
  const int lane = t & 63;
  const int wave = t >> 6;
  const int wm = wave >> 2;      // 0..1  (row halves of 64)
  const int wn = wave & 3;       // 0..3  (col quarters of 64)
  const int lrow = lane & 15;
  const int lgrp = lane >> 4;    // k-octet 0..3

  // XCD mapping: XCD owns a 16-tile m-band (2048 rows, A-band 4 MB L2-resident);
  // m fast, n slow. Bijective over 2048 blocks.
  const int bid = blockIdx.x;
  const int xcd = bid & 7;
  const int j   = bid >> 3;                    // 0..255
  const int m0 = (xcd * 16 + (j & 15)) * 128;  // 128 m-tiles
  const int n0 = (j >> 4) * 256;               // 16 n-tiles

  // staging context: slot s = wave*64+lane; rp = s>>3, phys chunk c = s&7;
  // logical l = c ^ (rp&7); source row = rp*2 + (l>>2), octet = l&3.
  {
  }
  const int s_   = wave * 64 + lane;
  const int rp_  = s_ >> 3, c_ = s_ & 7;
  const int l_   = c_ ^ (rp_ & 7);
  const int srow = rp_ * 2 + (l_ >> 2);
  const int gofs = (l_ & 3) * 8;
  Stage st;
  st.asrc  = xbf + (size_t)(m0 + srow) * D_DIM + gofs;
  st.bsrc0 = zbf + (size_t)(n0 + srow) * D_DIM + gofs;
  st.bsrc1 = zbf + (size_t)(n0 + 128 + srow) * D_DIM + gofs;
  st.dofs  = wave * 512;

  // fragment read offsets (ushort): row -> rp, phys chunk
  int aofs[4], bofs[4];
#pragma unroll
  for (int mi = 0; mi < 4; ++mi) {
    const int row = wm * 64 + mi * 16 + lrow;
    const int rp = row >> 1;
    const int cc = (((row & 1) << 2) | lgrp) ^ (rp & 7);
    aofs[mi] = rp * 64 + cc * 8;
  }
#pragma unroll
  for (int ni = 0; ni < 4; ++ni) {
    const int row = wn * 64 + ni * 16 + lrow;
    const int rp = row >> 1;
    const int cc = (((row & 1) << 2) | lgrp) ^ (rp & 7);
    bofs[ni] = 4096 + rp * 64 + cc * 8;
  }

  f32x4 acc[4][4] = {};

  // ---- prologue: stage tile0 -> buf0, tile1 -> buf1 (6 loads in flight)
  do_stage(st, lds, 0, 0);
  do_stage(st, lds, 12288, 32);

  // ---- 32 K-tiles: 10 triples + 2 tail. body<R,S,stage,vmcnt>(... k of t+2)
#pragma unroll 1
  for (int io = 0; io < 10; ++io) {
    const int kb = io * 96;
    body<0,     24576, true, 3>(acc, lds, aofs, bofs, st, lds, kb + 64);
    body<12288, 0,     true, 3>(acc, lds, aofs, bofs, st, lds, kb + 96);
    body<24576, 12288, true, 3>(acc, lds, aofs, bofs, st, lds, kb + 128);
  }
  body<0,     0, false, 3>(acc, lds, aofs, bofs, st, lds, 0);  // t=30
  body<12288, 0, false, 0>(acc, lds, aofs, bofs, st, lds, 0);  // t=31

  // ---- epilogue: arg = (cosh/zn)*xz - sinh*beta;
  // y = 0.5*(e - 1/e), e = exp2(copysign(zn,arg)*log2(ax+sqrt(ax^2+1)) + bias*log2e)
  // ni-innermost: 4 stores complete 256B row segments (no write amplification).
  float4 pq[4];
#pragma unroll
  for (int ni = 0; ni < 4; ++ni) pq[ni] = zp[n0 + wn * 64 + ni * 16 + lrow];
  const int ocol0 = n0 + wn * 64 + lrow;

#pragma unroll
  for (int mi = 0; mi < 4; ++mi) {
    const int r0 = m0 + wm * 64 + mi * 16 + lgrp * 4;
    const float4 b4 = *reinterpret_cast<const float4*>(&beta[r0]);
    const float btv[4] = {b4.x, b4.y, b4.z, b4.w};
#pragma unroll
    for (int jj = 0; jj < 4; ++jj) {
      const size_t rowbase = (size_t)(r0 + jj) * OUT_N + ocol0;
#pragma unroll
      for (int ni = 0; ni < 4; ++ni) {
        float acv = acc[mi][ni][jj];
        float arg = fmaf(pq[ni].x, acv, -(pq[ni].y * btv[jj]));
        float ax  = fminf(fabsf(arg), 1e6f);
        float s   = __builtin_amdgcn_sqrtf(fmaf(ax, ax, 1.0f));
        float tl  = __builtin_amdgcn_logf(ax + s);          // log2(ax + sqrt(ax^2+1))
        float zs  = copysignf(pq[ni].z, arg);
        float e   = __builtin_amdgcn_exp2f(fmaf(zs, tl, pq[ni].w));
        float rc  = __builtin_amdgcn_rcpf(e);
        out[rowbase + ni * 16] = fmaf(-0.5f, rc, 0.5f * e);
      }
    }
  }
}

// ---------------- launch ----------------

extern "C" void kernel_launch(void* const* d_in, const int* in_sizes, int n_in,
                              void* d_out, int out_size, void* d_ws, size_t ws_size,
                              hipStream_t stream) {
  const float* x    = (const float*)d_in[0];
  const float* z    = (const float*)d_in[1];
  const float* r    = (const float*)d_in[2];
  const float* bias = (const float*)d_in[3];
  float* out = (float*)d_out;

  char* ws = (char*)d_ws;
  unsigned short* xbf = (unsigned short*)ws;                               // 32 MB
  unsigned short* zbf = (unsigned short*)(ws + (size_t)32 * 1024 * 1024);  //  8 MB
  float* beta = (float*)(ws + (size_t)40 * 1024 * 1024);                   // 64 KB
  float4* zp  = (float4*)(ws + (size_t)40 * 1024 * 1024 + 64 * 1024);      // 64 KB

  prep_kernel<<<dim3((B_ROWS + OUT_N) / 4), dim3(256), 0, stream>>>(
      x, z, r, bias, xbf, zbf, beta, zp);
  gemm_fused<<<dim3((B_ROWS / 128) * (OUT_N / 256)), dim3(512), 0, stream>>>(
      xbf, zbf, beta, zp, out);
}

// Round 12
// 196.244 us; speedup vs baseline: 1.0611x; 1.0611x over previous
//
#include <hip/hip_runtime.h>
#include <stdint.h>
#include <math.h>

// Problem constants (fixed by setup_inputs)
#define B_ROWS 16384
#define D_DIM  1024
#define OUT_N  4096

typedef __bf16 bf16x8 __attribute__((ext_vector_type(8)));
typedef float  f32x4  __attribute__((ext_vector_type(4)));

__device__ __forceinline__ unsigned short f2bf(float f) {
  union { float f; uint32_t u; } v; v.f = f;
  uint32_t u = v.u;
  u += 0x7FFFu + ((u >> 16) & 1u);   // round-to-nearest-even
  return (unsigned short)(u >> 16);
}

// ---------------- prep kernel: one row per wave, no LDS/barriers ----------------
__global__ void prep_kernel(const float* __restrict__ x,
                            const float* __restrict__ z,
                            const float* __restrict__ r,
                            const float* __restrict__ bias,
                            unsigned short* __restrict__ xbf,
                            unsigned short* __restrict__ zbf,
                            float* __restrict__ beta,
                            float4* __restrict__ zp) {
  const int wave = threadIdx.x >> 6;
  const int lane = threadIdx.x & 63;
  const int b = blockIdx.x * 4 + wave;        // global row id
  const bool isx = (b < B_ROWS);
  const int row = isx ? b : (b - B_ROWS);
  const float* src = (isx ? x : z) + (size_t)row * D_DIM;
  unsigned short* dst = (isx ? xbf : zbf) + (size_t)row * D_DIM;

  float ssq = 0.0f;
#pragma unroll
  for (int i = 0; i < 4; ++i) {
    const float4 v = reinterpret_cast<const float4*>(src)[i * 64 + lane];
    ssq += v.x * v.x + v.y * v.y + v.z * v.z + v.w * v.w;
    ushort4 h;
    h.x = f2bf(v.x); h.y = f2bf(v.y); h.z = f2bf(v.z); h.w = f2bf(v.w);
    reinterpret_cast<ushort4*>(dst)[i * 64 + lane] = h;
  }
#pragma unroll
  for (int off = 32; off > 0; off >>= 1) ssq += __shfl_down(ssq, off);
  if (lane == 0) {
    if (isx) {
      beta[row] = sqrtf(1.0f + ssq);   // sqrt(1 - K*x^2), K = -1
    } else {
      float zn = fmaxf(sqrtf(ssq), 1e-15f);
      float sr = fminf(fmaxf(r[row], -15.0f), 15.0f);
      float ch = coshf(sr), sh = sinhf(sr);
      const float LOG2E = 1.4426950408889634f;
      zp[row] = make_float4(ch / zn, sh, zn, bias[row] * LOG2E);
    }
  }
}

// ------- fused GEMM: 256x256 tile, BK=32, 3-buf rotation, 1 barrier/phase -------

__device__ __forceinline__ void gload_lds16(const void* g, void* l) {
  __builtin_amdgcn_global_load_lds((__attribute__((address_space(1))) void*)g,
                                   (__attribute__((address_space(3))) void*)l,
                                   16, 0, 0);
}

#define FENCE() asm volatile("" ::: "memory")
#define BARRIER() do { FENCE(); __builtin_amdgcn_s_barrier(); FENCE(); } while (0)

// LDS (ushort offsets), buffer stride 16384 (32 KB):
//   A: [128 rowpairs][8 chunks16B] = 8192 ushorts (256 rows x 32 cols bf16)
//   B: same, at +8192
// Swizzle: logical chunk l of rowpair rp lives at phys chunk l ^ (rp&7), where
// logical l = (row&1)*4 + k_octet. Staging writes are LINEAR in chunk slots
// (gload_lds constraint); inverse swizzle folded into the per-lane GLOBAL
// source address (rule #21). Frag b128 reads: conflict-free (R11-verified: 0).

struct Stage {
  const unsigned short *asrc, *bsrc;  // row+octet folded in (chunk s)
  int dofs;                           // s*8 ushorts
};

// one K-tile stage = 4 gload_lds per thread (A 2, B 2); vmcnt +4
__device__ __forceinline__ void do_stage(const Stage& st, unsigned short* lds,
                                         int bufS, int k0) {
  gload_lds16(st.asrc + k0,                lds + bufS + st.dofs);
  gload_lds16(st.asrc + 128 * D_DIM + k0,  lds + bufS + st.dofs + 4096);
  gload_lds16(st.bsrc + k0,                lds + bufS + 8192 + st.dofs);
  gload_lds16(st.bsrc + 128 * D_DIM + k0,  lds + bufS + 8192 + st.dofs + 4096);
}

template <int BUFR, int BUFS, bool STG, int VMN>
__device__ __forceinline__ void body(f32x4 acc[8][4], const unsigned short* lds,
                                     const int aofs[8], const int bofs[4],
                                     const Stage& st, unsigned short* ldsw, int k0) {
  if (VMN == 0) asm volatile("s_waitcnt vmcnt(0)" ::: "memory");
  else          asm volatile("s_waitcnt vmcnt(4)" ::: "memory");
  BARRIER();
  bf16x8 af[8], bf_[4];
#pragma unroll
  for (int mi = 0; mi < 8; ++mi)
    af[mi] = *reinterpret_cast<const bf16x8*>(&lds[BUFR + aofs[mi]]);
#pragma unroll
  for (int ni = 0; ni < 4; ++ni)
    bf_[ni] = *reinterpret_cast<const bf16x8*>(&lds[BUFR + bofs[ni]]);
  if (STG) do_stage(st, ldsw, BUFS, k0);
  __builtin_amdgcn_s_setprio(1);
#pragma unroll
  for (int mi = 0; mi < 8; ++mi)
#pragma unroll
    for (int ni = 0; ni < 4; ++ni)
      acc[mi][ni] = __builtin_amdgcn_mfma_f32_16x16x32_bf16(
          af[mi], bf_[ni], acc[mi][ni], 0, 0, 0);
  __builtin_amdgcn_s_setprio(0);
}

// 1 block/CU (96 KB LDS), 2 waves/SIMD -> 256-reg budget; peak live ~200.
// RACE-FREE BY ROTATION (R11-proven): phase t reads buf(t%3), stages tile t+2
// into buf((t+2)%3) = the buffer phase t-1 read; the phase-t barrier guarantees
// all waves' t-1 ds_reads completed (lgkm-drained before their MFMA issue).
__global__ __launch_bounds__(512) void gemm_fused(
    const unsigned short* __restrict__ xbf,
    const unsigned short* __restrict__ zbf,
    const float* __restrict__ beta,
    const float4* __restrict__ zp,
    float* __restrict__ out) {
  __shared__ unsigned short lds[49152];   // 96 KB = 3 bufs x 32 KB

  const int t = threadIdx.x;
  const int lane = t & 63;
  const int wave = t >> 6;
  const int wm = wave >> 2;      // 0..1  (128-row half)
  const int wn = wave & 3;       // 0..3  (64-col quarter)
  const int lrow = lane & 15;
  const int lgrp = lane >> 4;    // k-octet 0..3

  // XCD mapping (R6-proven, FETCH ~99 MB): XCD owns an 8-tile m-band (A 4 MB
  // L2-resident); m fast, n slow. Bijective over 1024 blocks.
  const int bid = blockIdx.x;
  const int xcd = bid & 7;
  const int j   = bid >> 3;
  const int m0 = (xcd * 8 + (j & 7)) * 256;
  const int n0 = (j >> 3) * 256;

  // staging context: chunk s = wave*64+lane; rp = s>>3, phys c = s&7;
  // logical l = c ^ (rp&7); source row = rp*2 + (l>>2), octet = l&3.
  const int s_   = wave * 64 + lane;
  const int rp_  = s_ >> 3, c_ = s_ & 7;
  const int l_   = c_ ^ (rp_ & 7);
  const int srow = rp_ * 2 + (l_ >> 2);
  const int gofs = (l_ & 3) * 8;
  Stage st;
  st.asrc = xbf + (size_t)(m0 + srow) * D_DIM + gofs;
  st.bsrc = zbf + (size_t)(n0 + srow) * D_DIM + gofs;
  st.dofs = s_ * 8;

  // fragment read offsets (ushort)
  int aofs[8], bofs[4];
#pragma unroll
  for (int mi = 0; mi < 8; ++mi) {
    const int row = wm * 128 + mi * 16 + lrow;
    const int rp = row >> 1;
    const int cc = (((row & 1) << 2) | lgrp) ^ (rp & 7);
    aofs[mi] = rp * 64 + cc * 8;
  }
#pragma unroll
  for (int ni = 0; ni < 4; ++ni) {
    const int row = wn * 64 + ni * 16 + lrow;
    const int rp = row >> 1;
    const int cc = (((row & 1) << 2) | lgrp) ^ (rp & 7);
    bofs[ni] = 8192 + rp * 64 + cc * 8;
  }

  f32x4 acc[8][4] = {};

  // ---- prologue: tile0 -> buf0, tile1 -> buf1 (8 loads in flight)
  do_stage(st, lds, 0, 0);
  do_stage(st, lds, 16384, 32);

  // ---- 32 K-tiles: 10 triples + 2 tail; body<readBuf, stageBuf, stg, vmcnt>
#pragma unroll 1
  for (int io = 0; io < 10; ++io) {
    const int kb = io * 96;
    body<0,     32768, true, 4>(acc, lds, aofs, bofs, st, lds, kb + 64);
    body<16384, 0,     true, 4>(acc, lds, aofs, bofs, st, lds, kb + 96);
    body<32768, 16384, true, 4>(acc, lds, aofs, bofs, st, lds, kb + 128);
  }
  body<0,     0, false, 4>(acc, lds, aofs, bofs, st, lds, 0);  // t=30 (buf0)
  body<16384, 0, false, 0>(acc, lds, aofs, bofs, st, lds, 0);  // t=31 (buf1)

  // ---- epilogue: arg = (cosh/zn)*xz - sinh*beta;
  // y = 0.5*(e - 1/e), e = exp2(copysign(zn,arg)*log2(ax+sqrt(ax^2+1)) + bias*log2e)
  // ni-innermost: 4 stores complete 256B row segments (no write amplification).
  float4 pq[4];
#pragma unroll
  for (int ni = 0; ni < 4; ++ni) pq[ni] = zp[n0 + wn * 64 + ni * 16 + lrow];
  const int ocol0 = n0 + wn * 64 + lrow;

#pragma unroll
  for (int mi = 0; mi < 8; ++mi) {
    const int r0 = m0 + wm * 128 + mi * 16 + lgrp * 4;
    const float4 b4 = *reinterpret_cast<const float4*>(&beta[r0]);
    const float btv[4] = {b4.x, b4.y, b4.z, b4.w};
#pragma unroll
    for (int jj = 0; jj < 4; ++jj) {
      const size_t rowbase = (size_t)(r0 + jj) * OUT_N + ocol0;
#pragma unroll
      for (int ni = 0; ni < 4; ++ni) {
        float acv = acc[mi][ni][jj];
        float arg = fmaf(pq[ni].x, acv, -(pq[ni].y * btv[jj]));
        float ax  = fminf(fabsf(arg), 1e6f);
        float s   = __builtin_amdgcn_sqrtf(fmaf(ax, ax, 1.0f));
        float tl  = __builtin_amdgcn_logf(ax + s);          // log2(ax + sqrt(ax^2+1))
        float zs  = copysignf(pq[ni].z, arg);
        float e   = __builtin_amdgcn_exp2f(fmaf(zs, tl, pq[ni].w));
        float rc  = __builtin_amdgcn_rcpf(e);
        out[rowbase + ni * 16] = fmaf(-0.5f, rc, 0.5f * e);
      }
    }
  }
}

// ---------------- launch ----------------

extern "C" void kernel_launch(void* const* d_in, const int* in_sizes, int n_in,
                              void* d_out, int out_size, void* d_ws, size_t ws_size,
                              hipStream_t stream) {
  const float* x    = (const float*)d_in[0];
  const float* z    = (const float*)d_in[1];
  const float* r    = (const float*)d_in[2];
  const float* bias = (const float*)d_in[3];
  float* out = (float*)d_out;

  char* ws = (char*)d_ws;
  unsigned short* xbf = (unsigned short*)ws;                               // 32 MB
  unsigned short* zbf = (unsigned short*)(ws + (size_t)32 * 1024 * 1024);  //  8 MB
  float* beta = (float*)(ws + (size_t)40 * 1024 * 1024);                   // 64 KB
  float4* zp  = (float4*)(ws + (size_t)40 * 1024 * 1024 + 64 * 1024);      // 64 KB

  prep_kernel<<<dim3((B_ROWS + OUT_N) / 4), dim3(256), 0, stream>>>(
      x, z, r, bias, xbf, zbf, beta, zp);
  gemm_fused<<<dim3((B_ROWS / 256) * (OUT_N / 256)), dim3(512), 0, stream>>>(
      xbf, zbf, beta, zp, out);
}